// Round 5
// baseline (304.613 us; speedup 1.0000x reference)
//
#include <hip/hip_runtime.h>

typedef float f32x4 __attribute__((ext_vector_type(4)));
typedef short s16x8 __attribute__((ext_vector_type(8)));

#define DEV __device__ __forceinline__

DEV short f2bf(float f) {
    union { float f; unsigned u; } v; v.f = f;
    unsigned r = v.u + 0x7fffu + ((v.u >> 16) & 1u);
    return (short)(r >> 16);
}
DEV float bf2f(short s) {
    union { unsigned u; float f; } v; v.u = ((unsigned)(unsigned short)s) << 16;
    return v.f;
}

// B=2, Q=K=2048, D=512, H=8, hd=64. KV padded: 2048 real + 1 zero-attn + 31 pad = 2080
#define SEQ    2048
#define DMODEL 512
#define KPAD   2080
#define NROWS  32768   /* B*H*SEQ flash output rows */

// ws layout (bytes). qn|kn|vn contiguous (single QKV GEMM A), weights contiguous.
#define OFF_QN   0ull            /* 4096*512*2  = 4,194,304 */
#define OFF_KN   4194304ull      /* 4160*512*2  = 4,259,840 */
#define OFF_VN   8454144ull      /* 4160*512*2  -> ends 12,713,984 */
#define OFF_QH   12845056ull     /* 4,194,304 */
#define OFF_KH   17039360ull     /* 4,259,840 -> ends 21,299,200 */
#define OFF_KB   21299200ull     /* key bias f32 2*2080*4 = 16,640 (old vhp region, now free) */
#define OFF_ML   21315840ull     /* (m,l) f32 3*32768*2*4 = 786,432 -> ends 22,102,272 */
#define OFF_VHT  25690112ull     /* 4,259,840 -> ends 29,949,952 */
#define OFF_AV   29949952ull     /* 4,194,304 */
#define OFF_WQT  34144256ull     /* WqT|WkT|WvT|WoT|gWT = 4*524,288 + 1,048,576 = 3,145,728 */
#define WS_NEEDED 37289984ull
// aliased (lifetimes disjoint):
#define OFF_ON   0ull            /* flash partials bf16 [3][32768][64] = 12,582,912 over qn|kn|vn */
#define OFF_AP   17039360ull     /* attn_proj f32 8,388,608 over kh + old-vhp (kb/ml dead by then) */

// ---------------------------------------------------------------- fused LayerNorm+cast (q,k,v)
__global__ __launch_bounds__(256) void ln_all(
    const float* __restrict__ q, const float* __restrict__ k, const float* __restrict__ v,
    const float* __restrict__ qg, const float* __restrict__ qb,
    const float* __restrict__ kg, const float* __restrict__ kb2,
    const float* __restrict__ vg, const float* __restrict__ vb,
    short* __restrict__ qn, short* __restrict__ kn, short* __restrict__ vn)
{
    int bid = blockIdx.x;
    const float *in, *gamma, *beta; short* out; int Sreal, Spad;
    if (bid < 1024)      { in=q; gamma=qg; beta=qb;  out=qn; Sreal=SEQ; Spad=SEQ;  }
    else if (bid < 2064) { bid-=1024; in=k; gamma=kg; beta=kb2; out=kn; Sreal=SEQ; Spad=KPAD; }
    else                 { bid-=2064; in=v; gamma=vg; beta=vb;  out=vn; Sreal=SEQ; Spad=KPAD; }

    int w = threadIdx.x >> 6, l = threadIdx.x & 63;
    int r = bid * 4 + w;
    short* op = out + (size_t)r * DMODEL + l * 8;
    s16x8 o = {0,0,0,0,0,0,0,0};
    if (r >= 2 * Spad) { *(s16x8*)op = o; return; }
    int b = r / Spad, j = r - b * Spad;
    if (j >= Sreal) {
        if (j == Sreal) {
            f32x4 b0 = *(const f32x4*)(beta + l*8);
            f32x4 b1 = *(const f32x4*)(beta + l*8 + 4);
            #pragma unroll
            for (int t=0;t<4;t++){ o[t]=f2bf(b0[t]); o[t+4]=f2bf(b1[t]); }
        }
        *(s16x8*)op = o; return;
    }
    const float* ip = in + ((size_t)b * Sreal + j) * DMODEL + l * 8;
    f32x4 x0 = *(const f32x4*)ip;
    f32x4 x1 = *(const f32x4*)(ip + 4);
    float s = x0[0]+x0[1]+x0[2]+x0[3]+x1[0]+x1[1]+x1[2]+x1[3];
    #pragma unroll
    for (int off=1; off<64; off<<=1) s += __shfl_xor(s, off);
    float mean = s * (1.0f/512.0f);
    float vs = 0.f;
    #pragma unroll
    for (int t=0;t<4;t++){ float d0=x0[t]-mean, d1=x1[t]-mean; vs += d0*d0 + d1*d1; }
    #pragma unroll
    for (int off=1; off<64; off<<=1) vs += __shfl_xor(vs, off);
    float rstd = rsqrtf(vs * (1.0f/512.0f) + 1e-5f);
    f32x4 g0 = *(const f32x4*)(gamma + l*8), g1 = *(const f32x4*)(gamma + l*8 + 4);
    f32x4 b0 = *(const f32x4*)(beta + l*8),  b1 = *(const f32x4*)(beta + l*8 + 4);
    #pragma unroll
    for (int t=0;t<4;t++){
        o[t]   = f2bf((x0[t]-mean)*rstd*g0[t] + b0[t]);
        o[t+4] = f2bf((x1[t]-mean)*rstd*g1[t] + b1[t]);
    }
    *(s16x8*)op = o;
}

// ---------------------------------------------------------------- all weights transpose+cast + kbias
// blocks 0..255 Wq, 256..511 Wk, 512..767 Wv, 768..1023 Wo, 1024..1535 gW, 1536..1552 kbias
__global__ __launch_bounds__(256) void wt_all(
    const float* __restrict__ Wq, const float* __restrict__ Wk,
    const float* __restrict__ Wv, const float* __restrict__ Wo,
    const float* __restrict__ gW, short* __restrict__ WT,
    const int* __restrict__ km, float* __restrict__ kbias)
{
    int bid = blockIdx.x;
    if (bid >= 1536) {
        int i = (bid - 1536) * 256 + threadIdx.x;
        if (i >= 2 * KPAD) return;
        int b = i / KPAD, j = i - b * KPAD;
        float v;
        if (j < SEQ)       v = km[b*SEQ + j] ? 0.0f : -1e30f;
        else if (j == SEQ) v = 0.0f;     // zero-attn slot (mask bit 1)
        else               v = -1e30f;   // pad rows
        kbias[i] = v;
        return;
    }
    const float* in; short* out; int K;
    if (bid < 1024) {
        int wsel = bid >> 8;
        in = (wsel==0) ? Wq : (wsel==1) ? Wk : (wsel==2) ? Wv : Wo;
        out = WT + (size_t)wsel * 262144;
        K = 512; bid &= 255;
    } else {
        in = gW; out = WT + 1048576; K = 1024; bid -= 1024;
    }
    __shared__ float t[32][33];
    int nt = 16;  // N=512 always
    int bx = bid % nt, by = bid / nt;
    int n0 = bx * 32, k0 = by * 32;
    int tx = threadIdx.x & 31, ty = threadIdx.x >> 5;
    #pragma unroll
    for (int i=0;i<4;i++)
        t[ty + i*8][tx] = in[(size_t)(k0 + ty + i*8) * 512 + n0 + tx];
    __syncthreads();
    #pragma unroll
    for (int i=0;i<4;i++)
        out[(size_t)(n0 + ty + i*8) * K + k0 + tx] = f2bf(t[tx][ty + i*8]);
}

// ---------------------------------------------------------------- fused QKV projection GEMM
// A = qn|kn|vn contiguous (12416,512) bf16; B = WqkvT (3 segs of (512,512)).
// seg0 -> qh bf16, seg1 -> khp bf16, seg2 -> vhT transposed bf16 [b][h][d][k].
__global__ __launch_bounds__(256) void qkv_gemm(
    const short* __restrict__ A, const short* __restrict__ WT,
    short* __restrict__ qh, short* __restrict__ khp, short* __restrict__ vhT)
{
    __shared__ short As[64*64];
    __shared__ short Bs[64*64];
    int tid = threadIdx.x;
    int w = tid >> 6, l = tid & 63;
    int lr = l & 15, lg = l >> 4;
    int tm = blockIdx.x >> 3, tn = blockIdx.x & 7;
    int seg = (tm < 64) ? 0 : (tm < 129) ? 1 : 2;
    const short* Bt = WT + (size_t)seg * 262144;
    int wm = w >> 1, wn = w & 1;
    int srow = tid >> 3, sslot = tid & 7;

    f32x4 acc[2][2];
    #pragma unroll
    for (int m=0;m<2;m++)
        #pragma unroll
        for (int n=0;n<2;n++) acc[m][n] = (f32x4){0.f,0.f,0.f,0.f};

    for (int k0 = 0; k0 < 512; k0 += 64) {
        #pragma unroll
        for (int i=0;i<2;i++){
            int row = i*32 + srow;
            int gslot = sslot ^ (row & 7);
            const short* ga = A  + (size_t)(tm*64 + row) * 512 + k0 + gslot*8;
            const short* gb = Bt + (size_t)(tn*64 + row) * 512 + k0 + gslot*8;
            short* la = As + (i*256 + w*64) * 8;
            short* lb = Bs + (i*256 + w*64) * 8;
            __builtin_amdgcn_global_load_lds((const __attribute__((address_space(1))) void*)ga,
                                             (__attribute__((address_space(3))) void*)la, 16, 0, 0);
            __builtin_amdgcn_global_load_lds((const __attribute__((address_space(1))) void*)gb,
                                             (__attribute__((address_space(3))) void*)lb, 16, 0, 0);
        }
        __syncthreads();
        #pragma unroll
        for (int s=0;s<2;s++){
            s16x8 af[2], bfr[2];
            #pragma unroll
            for (int m=0;m<2;m++){
                int row = wm*32 + m*16 + lr;
                int slot = (s*4 + lg) ^ (row & 7);
                af[m] = *(const s16x8*)(As + row*64 + slot*8);
            }
            #pragma unroll
            for (int n=0;n<2;n++){
                int row = wn*32 + n*16 + lr;
                int slot = (s*4 + lg) ^ (row & 7);
                bfr[n] = *(const s16x8*)(Bs + row*64 + slot*8);
            }
            #pragma unroll
            for (int m=0;m<2;m++)
                #pragma unroll
                for (int n=0;n<2;n++)
                    acc[m][n] = __builtin_amdgcn_mfma_f32_16x16x32_bf16(af[m], bfr[n], acc[m][n], 0, 0, 0);
        }
        __syncthreads();
    }

    #pragma unroll
    for (int n=0;n<2;n++){
        int col = tn*64 + wn*32 + n*16 + lr;
        #pragma unroll
        for (int m=0;m<2;m++){
            #pragma unroll
            for (int j=0;j<4;j++){
                int row = tm*64 + wm*32 + m*16 + lg*4 + j;
                short v = f2bf(acc[m][n][j]);
                if (seg == 0) {
                    qh[(size_t)row*512 + col] = v;
                } else if (seg == 1) {
                    khp[(size_t)(row - 4096)*512 + col] = v;
                } else {
                    int r2 = row - 8256;
                    int b = (r2 >= KPAD) ? 1 : 0;
                    int kk = r2 - b*KPAD;
                    int h = col >> 6, d = col & 63;
                    vhT[((size_t)((b*8 + h)*64) + d)*KPAD + kk] = v;
                }
            }
        }
    }
}

// ---------------------------------------------------------------- bf16 GEMM 64x64 tile (Wo)
__global__ __launch_bounds__(256) void gemm64f(
    const short* __restrict__ A, const short* __restrict__ Bt,
    float* __restrict__ C, int M, int N, int K)
{
    __shared__ short As[64*64];
    __shared__ short Bs[64*64];
    int tid = threadIdx.x;
    int w = tid >> 6, l = tid & 63;
    int lr = l & 15, lg = l >> 4;
    int nt = N >> 6;
    int tm = blockIdx.x / nt, tn = blockIdx.x - tm * nt;
    int wm = w >> 1, wn = w & 1;
    int srow = tid >> 3, sslot = tid & 7;

    f32x4 acc[2][2];
    #pragma unroll
    for (int m=0;m<2;m++)
        #pragma unroll
        for (int n=0;n<2;n++) acc[m][n] = (f32x4){0.f,0.f,0.f,0.f};

    for (int k0 = 0; k0 < K; k0 += 64) {
        #pragma unroll
        for (int i=0;i<2;i++){
            int row = i*32 + srow;
            int gslot = sslot ^ (row & 7);
            const short* ga = A  + (size_t)(tm*64 + row) * K + k0 + gslot*8;
            const short* gb = Bt + (size_t)(tn*64 + row) * K + k0 + gslot*8;
            short* la = As + (i*256 + w*64) * 8;
            short* lb = Bs + (i*256 + w*64) * 8;
            __builtin_amdgcn_global_load_lds((const __attribute__((address_space(1))) void*)ga,
                                             (__attribute__((address_space(3))) void*)la, 16, 0, 0);
            __builtin_amdgcn_global_load_lds((const __attribute__((address_space(1))) void*)gb,
                                             (__attribute__((address_space(3))) void*)lb, 16, 0, 0);
        }
        __syncthreads();
        #pragma unroll
        for (int s=0;s<2;s++){
            s16x8 af[2], bfr[2];
            #pragma unroll
            for (int m=0;m<2;m++){
                int row = wm*32 + m*16 + lr;
                int slot = (s*4 + lg) ^ (row & 7);
                af[m] = *(const s16x8*)(As + row*64 + slot*8);
            }
            #pragma unroll
            for (int n=0;n<2;n++){
                int row = wn*32 + n*16 + lr;
                int slot = (s*4 + lg) ^ (row & 7);
                bfr[n] = *(const s16x8*)(Bs + row*64 + slot*8);
            }
            #pragma unroll
            for (int m=0;m<2;m++)
                #pragma unroll
                for (int n=0;n<2;n++)
                    acc[m][n] = __builtin_amdgcn_mfma_f32_16x16x32_bf16(af[m], bfr[n], acc[m][n], 0, 0, 0);
        }
        __syncthreads();
    }

    #pragma unroll
    for (int n=0;n<2;n++){
        int col = tn*64 + wn*32 + n*16 + lr;
        #pragma unroll
        for (int m=0;m<2;m++){
            #pragma unroll
            for (int j=0;j<4;j++){
                int row = tm*64 + wm*32 + m*16 + lg*4 + j;
                C[(size_t)row*N + col] = acc[m][n][j];
            }
        }
    }
}

// ---------------------------------------------------------------- gate GEMM (fused concat + sigmoid combine)
__global__ __launch_bounds__(256) void gate_gemm(
    const float* __restrict__ query, const float* __restrict__ ap,
    const short* __restrict__ gWT, const float* __restrict__ gB,
    float* __restrict__ out)
{
    __shared__ short As[64*64];
    __shared__ short Bs[64*64];
    int tid = threadIdx.x;
    int w = tid >> 6, l = tid & 63;
    int lr = l & 15, lg = l >> 4;
    int tm = blockIdx.x >> 3, tn = blockIdx.x & 7;
    int wm = w >> 1, wn = w & 1;
    int srow = tid >> 3, sslot = tid & 7;

    f32x4 acc[2][2];
    #pragma unroll
    for (int m=0;m<2;m++)
        #pragma unroll
        for (int n=0;n<2;n++) acc[m][n] = (f32x4){0.f,0.f,0.f,0.f};

    for (int k0 = 0; k0 < 1024; k0 += 64) {
        const float* src = (k0 < 512) ? query : ap;
        int csub = (k0 < 512) ? k0 : k0 - 512;
        #pragma unroll
        for (int i=0;i<2;i++){
            int row = i*32 + srow;
            const float* gp = src + (size_t)(tm*64 + row) * 512 + csub + sslot*8;
            f32x4 a0 = *(const f32x4*)gp;
            f32x4 a1 = *(const f32x4*)(gp + 4);
            s16x8 o;
            #pragma unroll
            for (int t=0;t<4;t++){ o[t] = f2bf(a0[t]); o[t+4] = f2bf(a1[t]); }
            int slot = sslot ^ (row & 7);
            *(s16x8*)(As + row*64 + slot*8) = o;
            int gslot = sslot ^ (row & 7);
            const short* gb = gWT + (size_t)(tn*64 + row) * 1024 + k0 + gslot*8;
            short* lb = Bs + (i*256 + w*64) * 8;
            __builtin_amdgcn_global_load_lds((const __attribute__((address_space(1))) void*)gb,
                                             (__attribute__((address_space(3))) void*)lb, 16, 0, 0);
        }
        __syncthreads();
        #pragma unroll
        for (int s=0;s<2;s++){
            s16x8 af[2], bfr[2];
            #pragma unroll
            for (int m=0;m<2;m++){
                int row = wm*32 + m*16 + lr;
                int slot = (s*4 + lg) ^ (row & 7);
                af[m] = *(const s16x8*)(As + row*64 + slot*8);
            }
            #pragma unroll
            for (int n=0;n<2;n++){
                int row = wn*32 + n*16 + lr;
                int slot = (s*4 + lg) ^ (row & 7);
                bfr[n] = *(const s16x8*)(Bs + row*64 + slot*8);
            }
            #pragma unroll
            for (int m=0;m<2;m++)
                #pragma unroll
                for (int n=0;n<2;n++)
                    acc[m][n] = __builtin_amdgcn_mfma_f32_16x16x32_bf16(af[m], bfr[n], acc[m][n], 0, 0, 0);
        }
        __syncthreads();
    }

    #pragma unroll
    for (int n=0;n<2;n++){
        int col = tn*64 + wn*32 + n*16 + lr;
        float badd = gB[col];
        #pragma unroll
        for (int m=0;m<2;m++){
            #pragma unroll
            for (int j=0;j<4;j++){
                int row = tm*64 + wm*32 + m*16 + lg*4 + j;
                size_t idx = (size_t)row*512 + col;
                float g = 1.0f / (1.0f + __expf(-(acc[m][n][j] + badd)));
                float q = query[idx], a = ap[idx];
                out[idx] = q + g*q + (1.0f - g)*a;
            }
        }
    }
}

// ---------------------------------------------------------------- flash attention, split-KV 3-way
// wid: [split:2(0..2)][b:1][h:3][qtile:7]. split0: kc 0..10, split1: 11..21,
// split2: 22..31 + 32-key tail. Early-V: V loads issued under the sum-reduce.
__global__ __launch_bounds__(256, 6) void flash_kernel(
    const short* __restrict__ qh, const short* __restrict__ kh,
    const short* __restrict__ vhT, const float* __restrict__ kbias,
    short* __restrict__ On, float* __restrict__ ml)
{
    __shared__ short plds[4][16*72];
    int tid = threadIdx.x;
    int w = tid >> 6, l = tid & 63;
    int wid = blockIdx.x * 4 + w;
    int split = wid >> 11;
    int b = (wid >> 10) & 1;
    int h = (wid >> 7) & 7;
    int q0 = (wid & 127) << 4;
    int cl = l & 15, rg = l >> 4;

    const short* qp = qh + ((size_t)(b*SEQ + q0 + cl))*DMODEL + h*64 + rg*8;
    s16x8 qf0 = *(const s16x8*)qp;
    s16x8 qf1 = *(const s16x8*)(qp + 32);

    f32x4 O[4];
    float mrow[4], lsum[4];
    #pragma unroll
    for (int n=0;n<4;n++) O[n] = (f32x4){0.f,0.f,0.f,0.f};
    #pragma unroll
    for (int j=0;j<4;j++){ mrow[j] = -1e30f; lsum[j] = 0.f; }

    const short* khb = kh + (size_t)b*KPAD*DMODEL + h*64;
    const short* vtb = vhT + (size_t)(b*8 + h)*64*KPAD;
    const float* kbb = kbias + b*KPAD;
    short* pl = plds[w];

    int kc0 = split * 11;
    int kcN = kc0 + ((split == 2) ? 10 : 11);
    for (int kc = kc0; kc < kcN; ++kc) {
        int k0 = kc * 64;
        float sv[4][4];
        #pragma unroll
        for (int nh=0; nh<4; ++nh) {
            const short* kp = khb + (size_t)(k0 + nh*16 + cl)*DMODEL + rg*8;
            s16x8 ka = *(const s16x8*)kp;
            s16x8 kb2 = *(const s16x8*)(kp + 32);
            f32x4 z = (f32x4){0.f,0.f,0.f,0.f};
            z = __builtin_amdgcn_mfma_f32_16x16x32_bf16(qf0, ka,  z, 0, 0, 0);
            z = __builtin_amdgcn_mfma_f32_16x16x32_bf16(qf1, kb2, z, 0, 0, 0);
            float bias = kbb[k0 + nh*16 + cl];
            #pragma unroll
            for (int j=0;j<4;j++) sv[nh][j] = fmaf(z[j], 0.125f, bias);
        }
        float ml4[4];
        #pragma unroll
        for (int j=0;j<4;j++)
            ml4[j] = fmaxf(fmaxf(sv[0][j], sv[1][j]), fmaxf(sv[2][j], sv[3][j]));
        #pragma unroll
        for (int off=1; off<16; off<<=1){
            #pragma unroll
            for (int j=0;j<4;j++) ml4[j] = fmaxf(ml4[j], __shfl_xor(ml4[j], off));
        }
        bool need = (ml4[0] > mrow[0]+8.f) || (ml4[1] > mrow[1]+8.f) ||
                    (ml4[2] > mrow[2]+8.f) || (ml4[3] > mrow[3]+8.f);
        if (__any(need)) {
            #pragma unroll
            for (int j=0;j<4;j++){
                float mn = fmaxf(mrow[j], ml4[j]);
                float sc = __expf(mrow[j] - mn);
                mrow[j] = mn; lsum[j] *= sc;
                #pragma unroll
                for (int n=0;n<4;n++) O[n][j] *= sc;
            }
        }
        float ps[4] = {0.f,0.f,0.f,0.f};
        #pragma unroll
        for (int nh=0; nh<4; ++nh){
            #pragma unroll
            for (int j=0;j<4;j++){
                float p = __expf(sv[nh][j] - mrow[j]);
                ps[j] += p;
                pl[(rg*4 + j)*72 + nh*16 + cl] = f2bf(p);
            }
        }
        // early-V: issue V loads so L2 latency hides under the sum-reduce + lds reads
        s16x8 vf[8];
        #pragma unroll
        for (int n=0;n<4;n++){
            vf[n*2]   = *(const s16x8*)(vtb + (size_t)(n*16 + cl)*KPAD + k0 + rg*8);
            vf[n*2+1] = *(const s16x8*)(vtb + (size_t)(n*16 + cl)*KPAD + k0 + 32 + rg*8);
        }
        #pragma unroll
        for (int off=1; off<16; off<<=1){
            #pragma unroll
            for (int j=0;j<4;j++) ps[j] += __shfl_xor(ps[j], off);
        }
        #pragma unroll
        for (int j=0;j<4;j++) lsum[j] += ps[j];

        s16x8 pa0 = *(const s16x8*)(pl + cl*72 + rg*8);
        s16x8 pa1 = *(const s16x8*)(pl + cl*72 + 32 + rg*8);
        __builtin_amdgcn_s_setprio(1);
        #pragma unroll
        for (int n=0;n<4;n++){
            O[n] = __builtin_amdgcn_mfma_f32_16x16x32_bf16(pa0, vf[n*2],   O[n], 0, 0, 0);
            O[n] = __builtin_amdgcn_mfma_f32_16x16x32_bf16(pa1, vf[n*2+1], O[n], 0, 0, 0);
        }
        __builtin_amdgcn_s_setprio(0);
    }

    if (split == 2) {  // tail: keys 2048..2079
        int k0 = 2048;
        float sv[2][4];
        #pragma unroll
        for (int nh=0; nh<2; ++nh) {
            const short* kp = khb + (size_t)(k0 + nh*16 + cl)*DMODEL + rg*8;
            s16x8 ka = *(const s16x8*)kp;
            s16x8 kb2 = *(const s16x8*)(kp + 32);
            f32x4 z = (f32x4){0.f,0.f,0.f,0.f};
            z = __builtin_amdgcn_mfma_f32_16x16x32_bf16(qf0, ka,  z, 0, 0, 0);
            z = __builtin_amdgcn_mfma_f32_16x16x32_bf16(qf1, kb2, z, 0, 0, 0);
            float bias = kbb[k0 + nh*16 + cl];
            #pragma unroll
            for (int j=0;j<4;j++) sv[nh][j] = fmaf(z[j], 0.125f, bias);
        }
        float ml4[4];
        #pragma unroll
        for (int j=0;j<4;j++) ml4[j] = fmaxf(sv[0][j], sv[1][j]);
        #pragma unroll
        for (int off=1; off<16; off<<=1){
            #pragma unroll
            for (int j=0;j<4;j++) ml4[j] = fmaxf(ml4[j], __shfl_xor(ml4[j], off));
        }
        bool need = (ml4[0] > mrow[0]+8.f) || (ml4[1] > mrow[1]+8.f) ||
                    (ml4[2] > mrow[2]+8.f) || (ml4[3] > mrow[3]+8.f);
        if (__any(need)) {
            #pragma unroll
            for (int j=0;j<4;j++){
                float mn = fmaxf(mrow[j], ml4[j]);
                float sc = __expf(mrow[j] - mn);
                mrow[j] = mn; lsum[j] *= sc;
                #pragma unroll
                for (int n=0;n<4;n++) O[n][j] *= sc;
            }
        }
        float ps[4] = {0.f,0.f,0.f,0.f};
        #pragma unroll
        for (int nh=0; nh<2; ++nh){
            #pragma unroll
            for (int j=0;j<4;j++){
                float p = __expf(sv[nh][j] - mrow[j]);
                ps[j] += p;
                pl[(rg*4 + j)*72 + nh*16 + cl] = f2bf(p);
            }
        }
        s16x8 vf[4];
        #pragma unroll
        for (int n=0;n<4;n++)
            vf[n] = *(const s16x8*)(vtb + (size_t)(n*16 + cl)*KPAD + k0 + rg*8);
        #pragma unroll
        for (int off=1; off<16; off<<=1){
            #pragma unroll
            for (int j=0;j<4;j++) ps[j] += __shfl_xor(ps[j], off);
        }
        #pragma unroll
        for (int j=0;j<4;j++) lsum[j] += ps[j];

        s16x8 pa0 = *(const s16x8*)(pl + cl*72 + rg*8);
        __builtin_amdgcn_s_setprio(1);
        #pragma unroll
        for (int n=0;n<4;n++)
            O[n] = __builtin_amdgcn_mfma_f32_16x16x32_bf16(pa0, vf[n], O[n], 0, 0, 0);
        __builtin_amdgcn_s_setprio(0);
    }

    // store normalized partial + (m, l)
    int rbase = ((b*8 + h) << 11) + q0;
    #pragma unroll
    for (int j=0;j<4;j++){
        int r = rbase + rg*4 + j;
        float invl = 1.0f / lsum[j];
        #pragma unroll
        for (int n=0;n<4;n++)
            On[((size_t)split*NROWS + r)*64 + n*16 + cl] = f2bf(O[n][j] * invl);
        if (cl == 0){
            ml[((size_t)split*NROWS + r)*2    ] = mrow[j];
            ml[((size_t)split*NROWS + r)*2 + 1] = lsum[j];
        }
    }
}

// ---------------------------------------------------------------- merge 3 split-KV partials -> av bf16
__global__ __launch_bounds__(256) void merge_kernel(
    const short* __restrict__ On, const float* __restrict__ ml,
    const int* __restrict__ qmask, short* __restrict__ av)
{
    int tid = threadIdx.x;
    int r = blockIdx.x * 32 + (tid >> 3);
    int d8 = (tid & 7) * 8;
    float m0 = ml[(size_t)r*2],              l0 = ml[(size_t)r*2 + 1];
    float m1 = ml[((size_t)NROWS + r)*2],    l1 = ml[((size_t)NROWS + r)*2 + 1];
    float m2 = ml[((size_t)2*NROWS + r)*2],  l2 = ml[((size_t)2*NROWS + r)*2 + 1];
    float m = fmaxf(m0, fmaxf(m1, m2));
    float w0 = l0 * __expf(m0 - m), w1 = l1 * __expf(m1 - m), w2 = l2 * __expf(m2 - m);
    int qrow = r & 2047, bh = r >> 11, h = bh & 7, b = bh >> 3;
    int qm = qmask[b*SEQ + qrow];
    float inv = qm ? 1.0f / (w0 + w1 + w2) : 0.0f;
    w0 *= inv; w1 *= inv; w2 *= inv;
    s16x8 o0 = *(const s16x8*)(On + (size_t)r*64 + d8);
    s16x8 o1 = *(const s16x8*)(On + ((size_t)NROWS + r)*64 + d8);
    s16x8 o2 = *(const s16x8*)(On + ((size_t)2*NROWS + r)*64 + d8);
    s16x8 o;
    #pragma unroll
    for (int e=0;e<8;e++) o[e] = f2bf(w0*bf2f(o0[e]) + w1*bf2f(o1[e]) + w2*bf2f(o2[e]));
    *(s16x8*)(av + ((size_t)(b*SEQ + qrow))*DMODEL + h*64 + d8) = o;
}

// ---------------------------------------------------------------- launch
extern "C" void kernel_launch(void* const* d_in, const int* in_sizes, int n_in,
                              void* d_out, int out_size, void* d_ws, size_t ws_size,
                              hipStream_t stream)
{
    const float* query = (const float*)d_in[0];
    const float* key   = (const float*)d_in[1];
    const float* value = (const float*)d_in[2];
    const float* Wq    = (const float*)d_in[3];
    const float* Wk    = (const float*)d_in[4];
    const float* Wv    = (const float*)d_in[5];
    const float* Wo    = (const float*)d_in[6];
    const float* gW    = (const float*)d_in[7];
    const float* gB    = (const float*)d_in[8];
    const float* qg    = (const float*)d_in[9];
    const float* qb    = (const float*)d_in[10];
    const float* kg    = (const float*)d_in[11];
    const float* kb    = (const float*)d_in[12];
    const float* vg    = (const float*)d_in[13];
    const float* vb    = (const float*)d_in[14];
    const int* qmask   = (const int*)d_in[15];
    const int* kmask   = (const int*)d_in[16];
    float* out = (float*)d_out;
    char* ws = (char*)d_ws;

    if (ws_size < WS_NEEDED) return;

    short* qn  = (short*)(ws + OFF_QN);
    short* kn  = (short*)(ws + OFF_KN);
    short* vn  = (short*)(ws + OFF_VN);
    short* qh  = (short*)(ws + OFF_QH);
    short* khp = (short*)(ws + OFF_KH);
    short* vhT = (short*)(ws + OFF_VHT);
    short* av  = (short*)(ws + OFF_AV);
    short* WT  = (short*)(ws + OFF_WQT);
    short* WoT = WT + 3*262144;
    short* gWT = WT + 1048576;
    short* On  = (short*)(ws + OFF_ON);
    float* mlp = (float*)(ws + OFF_ML);
    float* kbp = (float*)(ws + OFF_KB);
    float* ap  = (float*)(ws + OFF_AP);

    // 1. layernorm + cast, all three tensors (K/V padded to 2080 rows/batch)
    ln_all<<<3104, 256, 0, stream>>>(query, key, value, qg, qb, kg, kb, vg, vb, qn, kn, vn);

    // 2. all weights -> bf16 transposed + kbias
    wt_all<<<1553, 256, 0, stream>>>(Wq, Wk, Wv, Wo, gW, WT, kmask, kbp);

    // 3. fused QKV projection (V written transposed)
    qkv_gemm<<<1552, 256, 0, stream>>>(qn, WT, qh, khp, vhT);

    // 4. flash attention, split-KV 3-way
    flash_kernel<<<1536, 256, 0, stream>>>(qh, khp, vhT, kbp, On, mlp);
    merge_kernel<<<1024, 256, 0, stream>>>(On, mlp, qmask, av);

    // 5. output projection (f32 out)
    gemm64f<<<512, 256, 0, stream>>>(av, WoT, ap, 4096, 512, 512);

    // 6. gate GEMM fused: concat-stage + sigmoid + residual
    gate_gemm<<<512, 256, 0, stream>>>(query, ap, gWT, gB, out);

    (void)in_sizes; (void)n_in; (void)out_size;
}